// Round 7
// baseline (433.734 us; speedup 1.0000x reference)
//
#include <hip/hip_runtime.h>

typedef unsigned short u16;
typedef __attribute__((ext_vector_type(4))) float f32x4;
typedef __attribute__((ext_vector_type(8))) short s16x8;
typedef __attribute__((ext_vector_type(4))) short s16x4;

__device__ __forceinline__ u16 f2bf(float f) {
  unsigned u = __float_as_uint(f);
  u += 0x7FFFu + ((u >> 16) & 1u);
  return (u16)(u >> 16);
}
__device__ __forceinline__ float bf2f(u16 h) {
  return __uint_as_float(((unsigned)h) << 16);
}

// ---------------- cast + hi/lo split ----------------
__global__ __launch_bounds__(256) void k_cast_split(
    const float* __restrict__ src, u16* __restrict__ hi, u16* __restrict__ lo, int n4) {
  int i = blockIdx.x * 256 + threadIdx.x;
  if (i >= n4) return;
  f32x4 v = ((const f32x4*)src)[i];
  s16x4 h, l;
#pragma unroll
  for (int e = 0; e < 4; ++e) {
    float f = v[e];
    u16 hb = f2bf(f);
    float r = f - bf2f(hb);
    h[e] = (short)hb;
    l[e] = (short)f2bf(r);
  }
  ((s16x4*)hi)[i] = h;
  ((s16x4*)lo)[i] = l;
}

__global__ __launch_bounds__(256) void k_cast_plain(
    const float* __restrict__ src, u16* __restrict__ dst, int n4) {
  int i = blockIdx.x * 256 + threadIdx.x;
  if (i >= n4) return;
  f32x4 v = ((const f32x4*)src)[i];
  s16x4 h;
#pragma unroll
  for (int e = 0; e < 4; ++e) h[e] = (short)f2bf(v[e]);
  ((s16x4*)dst)[i] = h;
}

// ---------------- async global->LDS ----------------
__device__ __forceinline__ void gl16(const u16* src, u16* dst) {
  __builtin_amdgcn_global_load_lds(
      (const __attribute__((address_space(1))) unsigned*)src,
      (__attribute__((address_space(3))) unsigned*)dst, 16, 0, 0);
}

// XCD-chunked bijective block swizzle (T1). Total blocks % 8 == 0 everywhere here.
__device__ __forceinline__ void swz_block(int& bn, int& bm, int& bz) {
  int gx = gridDim.x, gy = gridDim.y;
  int flat = blockIdx.x + gx * (blockIdx.y + gy * blockIdx.z);
  int nwg = gx * gy * (int)gridDim.z;
  int q = nwg >> 3;
  int id = (flat & 7) * q + (flat >> 3);
  bn = id % gx;
  id /= gx;
  bm = id % gy;
  bz = id / gy;
}

// ---------------- B^T GEMM, 256x256 block, 8 waves (2x4), 8-phase + reg pipeline --
// Split-as-K: K_eff = NSEG*SK; seg0 Ah*Bh, seg1 Ah*Bl, seg2 Al*Bh.
// K-tile 64 as two K-half regions [kh][256][32] per operand per buffer (dbuf 128K).
// Fragment reads run ONE PHASE AHEAD into alternate register banks, so each
// pre-MFMA wait is a counted lgkmcnt(4/8) covering reads issued a full phase
// earlier. vmcnt(6) once per tile (after q3's STAGE, before next-tile reads).
// EPI 0: bf16 store  EPI 1: fp32 store *scale  EPI 2: qkv slab split  EPI 3: scores
template <int NSEG, int SK, int EPI>
__global__ __launch_bounds__(512, 2) void k_gemm(
    const u16* __restrict__ Ah, const u16* __restrict__ Al, int lda, long long aZ,
    const u16* __restrict__ Bh, const u16* __restrict__ Bl, int ldb, long long bZ,
    void* __restrict__ Cp, int ldc, long long cZ, float scale) {
  __shared__ u16 lds[2 * 32768];  // 2 bufs x (A 16384 + B 16384) u16 = 128 KiB
  int bn, bm, bz;
  swz_block(bn, bm, bz);
  const int tid = threadIdx.x;
  const int lane = tid & 63, wid = tid >> 6;
  const int wr = wid >> 2, wc = wid & 3;
  const u16 *A0h, *A0l = nullptr, *B0h, *B0l = nullptr;
  if constexpr (EPI == 3) {
    size_t zo = (size_t)(bz >> 1) * 8388608 + (size_t)(bz & 1) * 1048576;
    A0h = Ah + zo + (size_t)bm * 256 * 512;
    A0l = A0h + 2097152;
    B0h = Ah + zo + 4194304 + (size_t)bn * 256 * 512;
    B0l = B0h + 2097152;
  } else {
    A0h = Ah + (size_t)bz * aZ + (size_t)bm * 256 * lda;
    B0h = Bh + (size_t)bz * bZ + (size_t)bn * 256 * ldb;
    if constexpr (NSEG == 3) {
      A0l = Al + (size_t)bz * aZ + (size_t)bm * 256 * lda;
      B0l = Bl + (size_t)bz * bZ + (size_t)bn * 256 * ldb;
    }
  }
  constexpr int TPS = SK >> 6;
  constexpr int NT = NSEG * TPS;

  auto STAGE = [&](int t, int op, int kh) {
    if (t >= NT) return;
    int seg = (NSEG == 3) ? (t / TPS) : 0;
    int kk = ((t - seg * TPS) << 6) + (kh << 5);
    const u16* g;
    int ld_;
    if (op == 0) { g = (NSEG == 3 && seg == 2) ? A0l : A0h; ld_ = lda; }
    else         { g = (NSEG == 3 && seg == 1) ? B0l : B0h; ld_ = ldb; }
    u16* dst = &lds[0] + (t & 1) * 32768 + op * 16384 + kh * 8192;
    int lc = ((tid & 3) ^ ((tid >> 3) & 3)) << 3;
    int r0 = tid >> 2;
    gl16(g + (size_t)r0 * ld_ + kk + lc, dst + tid * 8);
    gl16(g + (size_t)(r0 + 128) * ld_ + kk + lc, dst + 4096 + tid * 8);
  };

  const int fr = lane & 15;
  const int pch = (((lane >> 4) ^ ((fr >> 1) & 3)) << 3);
  const int abase = (wr * 128 + fr) * 32 + pch;
  const int bbase = 16384 + (wc * 64 + fr) * 32 + pch;

  s16x8 a0[4], a1[4], b0[4], b1[4];
  f32x4 acc[8][4] = {};

  auto RD_A = [&](s16x8 (&dst)[4], int c, int mo, int kh) {
#pragma unroll
    for (int m = 0; m < 4; ++m)
      dst[m] = *(const s16x8*)&lds[c * 32768 + abase + kh * 8192 + mo + m * 512];
  };
  auto RD_B = [&](s16x8 (&dst)[4], int c, int kh) {
#pragma unroll
    for (int n = 0; n < 4; ++n)
      dst[n] = *(const s16x8*)&lds[c * 32768 + bbase + kh * 8192 + n * 512];
  };
  auto MM = [&](s16x8 (&av)[4], s16x8 (&bv)[4], int mo) {
    __builtin_amdgcn_s_setprio(1);
#pragma unroll
    for (int m = 0; m < 4; ++m)
#pragma unroll
      for (int n = 0; n < 4; ++n)
        acc[m + mo][n] =
            __builtin_amdgcn_mfma_f32_16x16x32_bf16(av[m], bv[n], acc[m + mo][n], 0, 0, 0);
    __builtin_amdgcn_s_setprio(0);
  };

  // prologue: tile0 fully, tile1 all but A.kh1 (staged at q0 of tile 0)
  STAGE(0, 0, 0); STAGE(0, 0, 1); STAGE(0, 1, 0); STAGE(0, 1, 1);
  STAGE(1, 1, 0); STAGE(1, 0, 0); STAGE(1, 1, 1);
  asm volatile("s_waitcnt vmcnt(6)" ::: "memory");  // tile0's 8 loads resident
  __builtin_amdgcn_s_barrier();
  RD_A(a0, 0, 0, 0);   // tile0 q0 fragments
  RD_B(b0, 0, 0);

#pragma unroll 1
  for (int T = 0; T < NT; ++T) {
    const int c = T & 1;
    // ---- q0: MFMA(m0-3,kh0); read-ahead a1 = A(m4-7,kh0) ----
    RD_A(a1, c, 2048, 0);
    STAGE(T + 1, 0, 1);
    __builtin_amdgcn_s_barrier();
    asm volatile("s_waitcnt lgkmcnt(4)" ::: "memory");  // drains q3(T-1)'s 8
    MM(a0, b0, 0);
    __builtin_amdgcn_s_barrier();
    // ---- q1: MFMA(m4-7,kh0); read-ahead a0 = A(m0-3,kh1), b1 = B(kh1) ----
    RD_A(a0, c, 0, 1);
    RD_B(b1, c, 1);
    STAGE(T + 2, 1, 0);
    __builtin_amdgcn_s_barrier();
    asm volatile("s_waitcnt lgkmcnt(8)" ::: "memory");  // drains q0's 4
    MM(a1, b0, 4);
    __builtin_amdgcn_s_barrier();
    // ---- q2: MFMA(m0-3,kh1); read-ahead a1 = A(m4-7,kh1) ----
    RD_A(a1, c, 2048, 1);
    STAGE(T + 2, 0, 0);
    __builtin_amdgcn_s_barrier();
    asm volatile("s_waitcnt lgkmcnt(4)" ::: "memory");  // drains q1's 8
    MM(a0, b1, 0);
    __builtin_amdgcn_s_barrier();
    // ---- q3: MFMA(m4-7,kh1); vmcnt; read-ahead next tile's q0 fragments ----
    STAGE(T + 2, 1, 1);
    if (T < NT - 1) {
      if (T == NT - 2)
        asm volatile("s_waitcnt vmcnt(0)" ::: "memory");
      else
        asm volatile("s_waitcnt vmcnt(6)" ::: "memory");  // tile T+1 resident
      RD_A(a0, c ^ 1, 0, 0);
      RD_B(b0, c ^ 1, 0);
      __builtin_amdgcn_s_barrier();
      asm volatile("s_waitcnt lgkmcnt(8)" ::: "memory");  // drains q2's 4
    } else {
      __builtin_amdgcn_s_barrier();
      asm volatile("s_waitcnt lgkmcnt(0)" ::: "memory");
    }
    MM(a1, b1, 4);
    __builtin_amdgcn_s_barrier();
  }

  const size_t zc = (size_t)bz * cZ;
#pragma unroll
  for (int m = 0; m < 8; ++m)
#pragma unroll
    for (int n = 0; n < 4; ++n)
#pragma unroll
      for (int r = 0; r < 4; ++r) {
        int row = bm * 256 + wr * 128 + m * 16 + (lane >> 4) * 4 + r;
        int col = bn * 256 + wc * 64 + n * 16 + fr;
        float f = acc[m][n][r];
        if constexpr (EPI == 0) {
          ((u16*)Cp)[zc + (size_t)row * ldc + col] = f2bf(f);
        } else if constexpr (EPI == 1 || EPI == 3) {
          ((float*)Cp)[zc + (size_t)row * ldc + col] = f * scale;
        } else {
          // qkv slab: 4 batch-pair slabs of 8,388,608 u16: [qh|ql|kh|kl]
          int bp = row >> 12;
          int rl = row & 4095;
          u16* slab = (u16*)Cp + (size_t)bp * 8388608;
          u16 h = f2bf(f);
          u16 l = f2bf(f - bf2f(h));
          if (col < 512) {
            slab[(size_t)rl * 512 + col] = h;
            slab[2097152 + (size_t)rl * 512 + col] = l;
          } else {
            slab[4194304 + (size_t)rl * 512 + (col - 512)] = h;
            slab[6291456 + (size_t)rl * 512 + (col - 512)] = l;
          }
        }
      }
}

// ---------------- row softmax + dropout mask -> P bf16 (4 batches / dispatch) ----
__global__ __launch_bounds__(256) void k_softmax(const float* __restrict__ sc,
                                                 u16* __restrict__ P,
                                                 const int* __restrict__ mask, int bp2) {
  const int rowp = blockIdx.x;  // 0..8191 (4 batches x 2048 rows)
  const int b = bp2 * 4 + (rowp >> 11), t = rowp & 2047;
  const float* srow = sc + (size_t)rowp * 2048;
  u16* prow = P + (size_t)b * 4194304 + (size_t)t * 2048;
  const int* mrow = mask + ((size_t)b * 2048 + t) * 2048;
  const int tid = threadIdx.x;
  float v[8];
#pragma unroll
  for (int j = 0; j < 8; ++j) v[j] = srow[tid + 256 * j];
  float m = v[0];
#pragma unroll
  for (int j = 1; j < 8; ++j) m = fmaxf(m, v[j]);
#pragma unroll
  for (int o = 32; o >= 1; o >>= 1) m = fmaxf(m, __shfl_xor(m, o));
  __shared__ float redm[4], reds[4];
  if ((tid & 63) == 0) redm[tid >> 6] = m;
  __syncthreads();
  m = fmaxf(fmaxf(redm[0], redm[1]), fmaxf(redm[2], redm[3]));
  float e[8], s = 0.f;
#pragma unroll
  for (int j = 0; j < 8; ++j) { e[j] = __expf(v[j] - m); s += e[j]; }
#pragma unroll
  for (int o = 32; o >= 1; o >>= 1) s += __shfl_xor(s, o);
  if ((tid & 63) == 0) reds[tid >> 6] = s;
  __syncthreads();
  s = reds[0] + reds[1] + reds[2] + reds[3];
  const float inv = 1.0f / (0.8f * s);
#pragma unroll
  for (int j = 0; j < 8; ++j) {
    int idx = tid + 256 * j;
    prow[idx] = mrow[idx] ? f2bf(e[j] * inv) : (u16)0;
  }
}

extern "C" void kernel_launch(void* const* d_in, const int* in_sizes, int n_in,
                              void* d_out, int out_size, void* d_ws, size_t ws_size,
                              hipStream_t stream) {
  const float* x  = (const float*)d_in[0];
  const float* Wq = (const float*)d_in[1];
  const float* Wk = (const float*)d_in[2];
  const float* Wv = (const float*)d_in[3];
  const int* mask = (const int*)d_in[4];
  float* out = (float*)d_out;

  // ws layout (u16 elements), total ~174 MB:
  u16* ws = (u16*)d_ws;
  u16* xh     = ws;                           // 16384x1024
  u16* xl     = xh + (size_t)16777216;
  u16* Whqk   = xl + (size_t)16777216;        // 1024x1024 (Wq rows 0-511 | Wk rows 512-1023)
  u16* Wlqk   = Whqk + (size_t)1048576;
  u16* Wvh    = Wlqk + (size_t)1048576;       // 1024x1024 plain bf16
  u16* qkslab = Wvh + (size_t)1048576;        // 4 slabs x 8388608 (later: P, 8x2048x2048)
  u16* vvt    = qkslab + (size_t)33554432;    // 1024 x 16384 (v^T, all batches)
  float* sc   = (float*)d_ws;                 // 4x2048x2048 fp32 = 67 MB, aliases xh+xl
                                              // (dead after QKV + vT GEMMs)

  k_cast_split<<<16384, 256, 0, stream>>>(x, xh, xl, 4194304);
  k_cast_split<<<512, 256, 0, stream>>>(Wq, Whqk, Wlqk, 131072);
  k_cast_split<<<512, 256, 0, stream>>>(Wk, Whqk + 524288, Wlqk + 524288, 131072);
  k_cast_plain<<<1024, 256, 0, stream>>>(Wv, Wvh, 262144);

  // q,k = x @ [Wq|Wk]^T  (3-term split folded into K: K_eff = 3072)
  dim3 gqk(4, 64, 1);
  k_gemm<3, 1024, 2><<<gqk, 512, 0, stream>>>(xh, xl, 1024, 0, Whqk, Wlqk, 1024, 0,
                                              qkslab, 0, 0, 0.f);

  // v^T = Wv @ x^T (plain bf16): C[g][t], coalesced
  dim3 gvt(64, 4, 1);
  k_gemm<1, 1024, 0><<<gvt, 512, 0, stream>>>(Wvh, (u16*)0, 1024, 0, xh, (u16*)0, 1024, 0,
                                              vvt, 16384, 0, 0.f);

  const float scale = 0.044194173824159216f;  // 1/sqrt(512)
  for (int bp2 = 0; bp2 < 2; ++bp2) {
    // scores for 4 batches (2 slabs), split-as-K (K_eff = 1536), z in [0,4)
    dim3 gs(8, 8, 4);
    k_gemm<3, 512, 3><<<gs, 512, 0, stream>>>(qkslab + (size_t)bp2 * 16777216, (u16*)0, 512, 0,
                                              (u16*)0, (u16*)0, 512, 0,
                                              sc, 2048, 4194304, scale);
    // softmax overwrites the (now dead) q/k slabs with P bf16 (linear per batch)
    k_softmax<<<8192, 256, 0, stream>>>(sc, qkslab, mask, bp2);
  }

  // out = P @ (v^T)^T for all 8 batches in one launch
  dim3 gpv(4, 8, 8);
  k_gemm<1, 2048, 1><<<gpv, 512, 0, stream>>>(qkslab, (u16*)0, 2048, 4194304,
                                              vvt, (u16*)0, 16384, 2048,
                                              out, 1024, 2097152, 1.0f);

  (void)in_sizes; (void)n_in; (void)out_size; (void)ws_size;
}

// Round 8
// 326.608 us; speedup vs baseline: 1.3280x; 1.3280x over previous
//
#include <hip/hip_runtime.h>

typedef unsigned short u16;
typedef _Float16 h16;
typedef __attribute__((ext_vector_type(4))) float f32x4;
typedef __attribute__((ext_vector_type(8))) _Float16 h16x8;
typedef __attribute__((ext_vector_type(4))) _Float16 h16x4;
typedef __attribute__((ext_vector_type(4))) int i32x4;

// ---------------- fp32 -> fp16 cast (RNE via v_cvt_f16_f32) ----------------
__global__ __launch_bounds__(256) void k_cast_h(
    const float* __restrict__ src, h16* __restrict__ dst, int n4) {
  int i = blockIdx.x * 256 + threadIdx.x;
  if (i >= n4) return;
  f32x4 v = ((const f32x4*)src)[i];
  h16x4 o;
#pragma unroll
  for (int e = 0; e < 4; ++e) o[e] = (h16)v[e];
  ((h16x4*)dst)[i] = o;
}

// ---------------- async global->LDS ----------------
__device__ __forceinline__ void gl16(const u16* src, u16* dst) {
  __builtin_amdgcn_global_load_lds(
      (const __attribute__((address_space(1))) unsigned*)src,
      (__attribute__((address_space(3))) unsigned*)dst, 16, 0, 0);
}

// XCD-chunked bijective block swizzle (T1). Total blocks % 8 == 0 everywhere here.
__device__ __forceinline__ void swz_block(int& bn, int& bm, int& bz) {
  int gx = gridDim.x, gy = gridDim.y;
  int flat = blockIdx.x + gx * (blockIdx.y + gy * blockIdx.z);
  int nwg = gx * gy * (int)gridDim.z;
  int q = nwg >> 3;
  int id = (flat & 7) * q + (flat >> 3);
  bn = id % gx;
  id /= gx;
  bm = id % gy;
  bz = id / gy;
}

// ---------------- B^T GEMM, 256x256 block, 8 waves (2x4), 8-phase, fp16 1-term ---
// K = NT*64. K-tile 64 as two K-half regions [kh][256][32] per operand per buffer
// (dbuf 128 KiB). Chunk swizzle pc = k8 ^ ((r>>1)&3), applied on the global source
// (linear gload_lds dest) and on the ds_read side (rule #21).
// Per tile: 4 phases {ds_read 4/8 b128 + stage 1 half-tile, barrier, lgkmcnt(0),
// setprio(1), 16 MFMA, setprio(0), barrier}; vmcnt(6) once per tile at q3.
// EPI 0: fp16 store  EPI 1: fp32 store *scale  EPI 2: q|k split fp16 store
template <int NT, int EPI>
__global__ __launch_bounds__(512, 2) void k_gemm(
    const u16* __restrict__ A, int lda, long long aZ,
    const u16* __restrict__ B, int ldb, long long bZ,
    void* __restrict__ Cp, int ldc, long long cZ, float scale) {
  __shared__ u16 lds[2 * 32768];  // 2 bufs x (A 16384 + B 16384) u16 = 128 KiB
  int bn, bm, bz;
  swz_block(bn, bm, bz);
  const int tid = threadIdx.x;
  const int lane = tid & 63, wid = tid >> 6;
  const int wr = wid >> 2, wc = wid & 3;
  const u16* A0 = A + (size_t)bz * aZ + (size_t)bm * 256 * lda;
  const u16* B0 = B + (size_t)bz * bZ + (size_t)bn * 256 * ldb;

  const int lc = ((tid & 3) ^ ((tid >> 3) & 3)) << 3;  // inverse-swizzled src chunk
  const int r0s = tid >> 2;

  auto STAGE = [&](int t, int op, int kh) {
    if (t >= NT) return;
    int kk = (t << 6) + (kh << 5);
    const u16* g = op ? B0 : A0;
    int ld_ = op ? ldb : lda;
    u16* dst = &lds[0] + (t & 1) * 32768 + op * 16384 + kh * 8192;
    gl16(g + (size_t)r0s * ld_ + kk + lc, dst + tid * 8);
    gl16(g + (size_t)(r0s + 128) * ld_ + kk + lc, dst + 4096 + tid * 8);
  };

  const int fr = lane & 15;
  const int pch = (((lane >> 4) ^ ((fr >> 1) & 3)) << 3);  // swizzled read chunk
  const int abase = (wr * 128 + fr) * 32 + pch;   // + m*512 + kh*8192
  const int bbase = 16384 + (wc * 64 + fr) * 32 + pch;  // + n*512 + kh*8192

  f32x4 acc[8][4] = {};

  // prologue: tile0 fully, tile1 all but A.kh1 (staged at q0 of tile 0)
  STAGE(0, 0, 0); STAGE(0, 0, 1); STAGE(0, 1, 0); STAGE(0, 1, 1);
  STAGE(1, 1, 0); STAGE(1, 0, 0); STAGE(1, 1, 1);
  asm volatile("s_waitcnt vmcnt(6)" ::: "memory");  // tile0's 8 loads resident
  __builtin_amdgcn_s_barrier();

  auto TILE = [&](int T, int c, bool drain) {
    const int cb = c * 32768;
    h16x8 av[4], bv[4];
    // ---- q0: A m0-3 kh0 + B n0-3 kh0 ----
#pragma unroll
    for (int n = 0; n < 4; ++n) bv[n] = *(const h16x8*)&lds[cb + bbase + n * 512];
#pragma unroll
    for (int m = 0; m < 4; ++m) av[m] = *(const h16x8*)&lds[cb + abase + m * 512];
    STAGE(T + 1, 0, 1);
    __builtin_amdgcn_s_barrier();
    asm volatile("s_waitcnt lgkmcnt(0)" ::: "memory");
    __builtin_amdgcn_s_setprio(1);
#pragma unroll
    for (int m = 0; m < 4; ++m)
#pragma unroll
      for (int n = 0; n < 4; ++n)
        acc[m][n] = __builtin_amdgcn_mfma_f32_16x16x32_f16(av[m], bv[n], acc[m][n], 0, 0, 0);
    __builtin_amdgcn_s_setprio(0);
    __builtin_amdgcn_s_barrier();
    // ---- q1: A m4-7 kh0 (B kh0 reused) ----
#pragma unroll
    for (int m = 0; m < 4; ++m) av[m] = *(const h16x8*)&lds[cb + abase + 2048 + m * 512];
    STAGE(T + 2, 1, 0);
    __builtin_amdgcn_s_barrier();
    asm volatile("s_waitcnt lgkmcnt(0)" ::: "memory");
    __builtin_amdgcn_s_setprio(1);
#pragma unroll
    for (int m = 0; m < 4; ++m)
#pragma unroll
      for (int n = 0; n < 4; ++n)
        acc[m + 4][n] = __builtin_amdgcn_mfma_f32_16x16x32_f16(av[m], bv[n], acc[m + 4][n], 0, 0, 0);
    __builtin_amdgcn_s_setprio(0);
    __builtin_amdgcn_s_barrier();
    // ---- q2: A m0-3 kh1 + B n0-3 kh1 ----
#pragma unroll
    for (int n = 0; n < 4; ++n) bv[n] = *(const h16x8*)&lds[cb + bbase + 8192 + n * 512];
#pragma unroll
    for (int m = 0; m < 4; ++m) av[m] = *(const h16x8*)&lds[cb + abase + 8192 + m * 512];
    STAGE(T + 2, 0, 0);
    __builtin_amdgcn_s_barrier();
    asm volatile("s_waitcnt lgkmcnt(0)" ::: "memory");
    __builtin_amdgcn_s_setprio(1);
#pragma unroll
    for (int m = 0; m < 4; ++m)
#pragma unroll
      for (int n = 0; n < 4; ++n)
        acc[m][n] = __builtin_amdgcn_mfma_f32_16x16x32_f16(av[m], bv[n], acc[m][n], 0, 0, 0);
    __builtin_amdgcn_s_setprio(0);
    __builtin_amdgcn_s_barrier();
    // ---- q3: A m4-7 kh1 ----
#pragma unroll
    for (int m = 0; m < 4; ++m) av[m] = *(const h16x8*)&lds[cb + abase + 8192 + 2048 + m * 512];
    STAGE(T + 2, 1, 1);
    if (drain)
      asm volatile("s_waitcnt vmcnt(0)" ::: "memory");
    else
      asm volatile("s_waitcnt vmcnt(6)" ::: "memory");  // tile T+1 resident
    __builtin_amdgcn_s_barrier();
    asm volatile("s_waitcnt lgkmcnt(0)" ::: "memory");
    __builtin_amdgcn_s_setprio(1);
#pragma unroll
    for (int m = 0; m < 4; ++m)
#pragma unroll
      for (int n = 0; n < 4; ++n)
        acc[m + 4][n] = __builtin_amdgcn_mfma_f32_16x16x32_f16(av[m], bv[n], acc[m + 4][n], 0, 0, 0);
    __builtin_amdgcn_s_setprio(0);
    __builtin_amdgcn_s_barrier();
  };

#pragma unroll 1
  for (int T = 0; T < NT; T += 2) {
    TILE(T, 0, T == NT - 2);
    TILE(T + 1, 1, T + 1 == NT - 1);
  }

  const size_t zc = (size_t)bz * cZ;
#pragma unroll
  for (int m = 0; m < 8; ++m)
#pragma unroll
    for (int n = 0; n < 4; ++n)
#pragma unroll
      for (int r = 0; r < 4; ++r) {
        int row = bm * 256 + wr * 128 + m * 16 + (lane >> 4) * 4 + r;
        int col = bn * 256 + wc * 64 + n * 16 + fr;
        float f = acc[m][n][r];
        if constexpr (EPI == 0) {
          ((h16*)Cp)[zc + (size_t)row * ldc + col] = (h16)f;
        } else if constexpr (EPI == 1) {
          ((float*)Cp)[zc + (size_t)row * ldc + col] = f * scale;
        } else {
          // q | k split: q at Cp, k at Cp + 8,388,608 (each 16384 x 512 h16)
          if (col < 512)
            ((h16*)Cp)[(size_t)row * 512 + col] = (h16)f;
          else
            ((h16*)Cp)[8388608 + (size_t)row * 512 + (col - 512)] = (h16)f;
        }
      }
}

// ---------------- row softmax + dropout mask -> P fp16 (2 batches / dispatch) ----
__global__ __launch_bounds__(256) void k_softmax(const float* __restrict__ sc,
                                                 h16* __restrict__ P,
                                                 const int* __restrict__ mask, int g) {
  const int rowp = blockIdx.x;  // 0..4095 (2 batches x 2048 rows)
  const int b = g * 2 + (rowp >> 11), t = rowp & 2047;
  const float* srow = sc + (size_t)rowp * 2048;
  h16* prow = P + (size_t)b * 4194304 + (size_t)t * 2048;
  const int* mrow = mask + ((size_t)b * 2048 + t) * 2048;
  const int tid = threadIdx.x;
  f32x4 v0 = ((const f32x4*)srow)[tid * 2];
  f32x4 v1 = ((const f32x4*)srow)[tid * 2 + 1];
  float v[8] = {v0[0], v0[1], v0[2], v0[3], v1[0], v1[1], v1[2], v1[3]};
  float m = v[0];
#pragma unroll
  for (int j = 1; j < 8; ++j) m = fmaxf(m, v[j]);
#pragma unroll
  for (int o = 32; o >= 1; o >>= 1) m = fmaxf(m, __shfl_xor(m, o));
  __shared__ float redm[4], reds[4];
  if ((tid & 63) == 0) redm[tid >> 6] = m;
  __syncthreads();
  m = fmaxf(fmaxf(redm[0], redm[1]), fmaxf(redm[2], redm[3]));
  float e[8], s = 0.f;
#pragma unroll
  for (int j = 0; j < 8; ++j) { e[j] = __expf(v[j] - m); s += e[j]; }
#pragma unroll
  for (int o = 32; o >= 1; o >>= 1) s += __shfl_xor(s, o);
  if ((tid & 63) == 0) reds[tid >> 6] = s;
  __syncthreads();
  s = reds[0] + reds[1] + reds[2] + reds[3];
  const float inv = 1.0f / (0.8f * s);
  i32x4 m0 = ((const i32x4*)mrow)[tid * 2];
  i32x4 m1 = ((const i32x4*)mrow)[tid * 2 + 1];
  int mm[8] = {m0[0], m0[1], m0[2], m0[3], m1[0], m1[1], m1[2], m1[3]};
  h16x8 o;
#pragma unroll
  for (int j = 0; j < 8; ++j) o[j] = mm[j] ? (h16)(e[j] * inv) : (h16)0.f;
  ((h16x8*)prow)[tid] = o;
}

extern "C" void kernel_launch(void* const* d_in, const int* in_sizes, int n_in,
                              void* d_out, int out_size, void* d_ws, size_t ws_size,
                              hipStream_t stream) {
  const float* x  = (const float*)d_in[0];
  const float* Wq = (const float*)d_in[1];
  const float* Wk = (const float*)d_in[2];
  const float* Wv = (const float*)d_in[3];
  const int* mask = (const int*)d_in[4];
  float* out = (float*)d_out;

  // ws layout (u16 elements), total 85,983,296 u16 = 172.0 MB:
  // [0]          xf   16384x1024 fp16 (dead after vT; sc aliases it)
  // [16777216]   Wqk  1024x1024 fp16 (Wq rows 0-511 | Wk rows 512-1023)
  // [17825792]   Wvf  1024x1024 fp16
  // [18874368]   q    8 x 2048x512 fp16   (k follows at +8388608)
  // [27262976]   k    8 x 2048x512 fp16
  // [35651584]   vvt  1024 x 16384 fp16 (v^T, all batches)
  // [52428864]   P    8 x 2048x2048 fp16 (compact)
  u16* ws = (u16*)d_ws;
  h16* xf  = (h16*)ws;
  h16* Wqk = (h16*)(ws + 16777216);
  h16* Wvf = (h16*)(ws + 17825792);
  h16* qb  = (h16*)(ws + 18874368);
  h16* vvt = (h16*)(ws + 35651584);
  h16* Pb  = (h16*)(ws + 52428864);
  float* sc = (float*)d_ws;  // 2 batches x 2048x2048 fp32 = 33.5 MB, aliases xf

  k_cast_h<<<16384, 256, 0, stream>>>(x, xf, 4194304);
  k_cast_h<<<512, 256, 0, stream>>>(Wq, Wqk, 131072);
  k_cast_h<<<512, 256, 0, stream>>>(Wk, Wqk + 524288, 131072);
  k_cast_h<<<1024, 256, 0, stream>>>(Wv, Wvf, 262144);

  // q,k = x @ [Wq|Wk]^T  (1-term fp16, K=1024)
  dim3 gqk(4, 64, 1);
  k_gemm<16, 2><<<gqk, 512, 0, stream>>>((const u16*)xf, 1024, 0,
                                         (const u16*)Wqk, 1024, 0, qb, 512, 0, 0.f);

  // v^T = Wv @ x^T: C[g][t], coalesced
  dim3 gvt(64, 4, 1);
  k_gemm<16, 0><<<gvt, 512, 0, stream>>>((const u16*)Wvf, 1024, 0,
                                         (const u16*)xf, 1024, 0, vvt, 16384, 0, 0.f);

  const float scale = 0.044194173824159216f;  // 1/sqrt(512)
  for (int g = 0; g < 4; ++g) {
    // scores for 2 batches (K=512), fp32 out into sc (aliases dead xf)
    dim3 gs(8, 8, 2);
    k_gemm<8, 1><<<gs, 512, 0, stream>>>(
        (const u16*)(qb + (size_t)g * 2097152), 512, 1048576,
        (const u16*)(qb + 8388608 + (size_t)g * 2097152), 512, 1048576,
        sc, 2048, 4194304, scale);
    k_softmax<<<4096, 256, 0, stream>>>(sc, Pb, mask, g);
  }

  // out = P @ (v^T)^T for all 8 batches in one launch (K=2048)
  dim3 gpv(4, 8, 8);
  k_gemm<32, 1><<<gpv, 512, 0, stream>>>((const u16*)Pb, 2048, 4194304,
                                         (const u16*)vvt, 16384, 2048,
                                         out, 1024, 2097152, 1.0f);

  (void)in_sizes; (void)n_in; (void)out_size; (void)ws_size;
}

// Round 9
// 268.398 us; speedup vs baseline: 1.6160x; 1.2169x over previous
//
#include <hip/hip_runtime.h>

typedef unsigned short u16;
typedef _Float16 h16;
typedef __attribute__((ext_vector_type(4))) float f32x4;
typedef __attribute__((ext_vector_type(8))) _Float16 h16x8;
typedef __attribute__((ext_vector_type(4))) _Float16 h16x4;
typedef __attribute__((ext_vector_type(4))) int i32x4;

// ---------------- fused fp32 -> fp16 cast for all 4 inputs ----------------
__global__ __launch_bounds__(256) void k_cast_all(
    const float* __restrict__ x, const float* __restrict__ wq,
    const float* __restrict__ wk, const float* __restrict__ wv,
    h16* __restrict__ xf, h16* __restrict__ wqk, h16* __restrict__ wvf) {
  int bid = blockIdx.x;
  const float* src;
  h16* dst;
  int idx;
  if (bid < 16384) { src = x;  dst = xf;           idx = bid * 256 + threadIdx.x; }
  else if (bid < 16896) { src = wq; dst = wqk;          idx = (bid - 16384) * 256 + threadIdx.x; }
  else if (bid < 17408) { src = wk; dst = wqk + 524288; idx = (bid - 16896) * 256 + threadIdx.x; }
  else { src = wv; dst = wvf;          idx = (bid - 17408) * 256 + threadIdx.x; }
  f32x4 v = ((const f32x4*)src)[idx];
  h16x4 o;
#pragma unroll
  for (int e = 0; e < 4; ++e) o[e] = (h16)v[e];
  ((h16x4*)dst)[idx] = o;
}

// ---------------- async global->LDS ----------------
__device__ __forceinline__ void gl16(const u16* src, u16* dst) {
  __builtin_amdgcn_global_load_lds(
      (const __attribute__((address_space(1))) unsigned*)src,
      (__attribute__((address_space(3))) unsigned*)dst, 16, 0, 0);
}

// XCD-chunked bijective block swizzle (T1). Total blocks % 8 == 0 everywhere here.
__device__ __forceinline__ void swz_block(int& bn, int& bm, int& bz) {
  int gx = gridDim.x, gy = gridDim.y;
  int flat = blockIdx.x + gx * (blockIdx.y + gy * blockIdx.z);
  int nwg = gx * gy * (int)gridDim.z;
  int q = nwg >> 3;
  int id = (flat & 7) * q + (flat >> 3);
  bn = id % gx;
  id /= gx;
  bm = id % gy;
  bz = id / gy;
}

// ---------------- B^T GEMM, 256x256 block, 8 waves (2x4), 8-phase, fp16 ----------
// K = NT*64. K-tile 64 as two K-half regions [kh][256][32] per operand per buffer
// (dbuf 128 KiB). Chunk swizzle pc = k8 ^ ((r>>1)&3) on the global source (linear
// gload_lds dest) and on the ds_read side (rule #21).
// Per tile: 4 phases {ds_read 4/8 b128 + stage 1 half-tile, barrier, lgkmcnt(0),
// setprio(1), 16 MFMA, setprio(0), barrier}; vmcnt(6) once per tile at q3.
// EPI 0: fp16 store   EPI 1: fp32 store *scale   EPI 4: fp16 store *scale
template <int NT, int EPI>
__global__ __launch_bounds__(512, 2) void k_gemm(
    const u16* __restrict__ A, int lda, long long aZ,
    const u16* __restrict__ B, int ldb, long long bZ,
    void* __restrict__ Cp, int ldc, long long cZ, float scale) {
  __shared__ u16 lds[2 * 32768];  // 2 bufs x (A 16384 + B 16384) u16 = 128 KiB
  int bn, bm, bz;
  swz_block(bn, bm, bz);
  const int tid = threadIdx.x;
  const int lane = tid & 63, wid = tid >> 6;
  const int wr = wid >> 2, wc = wid & 3;
  const u16* A0 = A + (size_t)bz * aZ + (size_t)bm * 256 * lda;
  const u16* B0 = B + (size_t)bz * bZ + (size_t)bn * 256 * ldb;

  const int lc = ((tid & 3) ^ ((tid >> 3) & 3)) << 3;  // inverse-swizzled src chunk
  const int r0s = tid >> 2;

  auto STAGE = [&](int t, int op, int kh) {
    if (t >= NT) return;
    int kk = (t << 6) + (kh << 5);
    const u16* g = op ? B0 : A0;
    int ld_ = op ? ldb : lda;
    u16* dst = &lds[0] + (t & 1) * 32768 + op * 16384 + kh * 8192;
    gl16(g + (size_t)r0s * ld_ + kk + lc, dst + tid * 8);
    gl16(g + (size_t)(r0s + 128) * ld_ + kk + lc, dst + 4096 + tid * 8);
  };

  const int fr = lane & 15;
  const int pch = (((lane >> 4) ^ ((fr >> 1) & 3)) << 3);  // swizzled read chunk
  const int abase = (wr * 128 + fr) * 32 + pch;        // + m*512 + kh*8192
  const int bbase = 16384 + (wc * 64 + fr) * 32 + pch; // + n*512 + kh*8192

  f32x4 acc[8][4] = {};

  // prologue: tile0 fully, tile1 all but A.kh1 (staged at q0 of tile 0)
  STAGE(0, 0, 0); STAGE(0, 0, 1); STAGE(0, 1, 0); STAGE(0, 1, 1);
  STAGE(1, 1, 0); STAGE(1, 0, 0); STAGE(1, 1, 1);
  asm volatile("s_waitcnt vmcnt(6)" ::: "memory");  // tile0's 8 loads resident
  __builtin_amdgcn_s_barrier();

  auto TILE = [&](int T, int c, bool drain) {
    const int cb = c * 32768;
    h16x8 av[4], bv[4];
    // ---- q0: A m0-3 kh0 + B n0-3 kh0 ----
#pragma unroll
    for (int n = 0; n < 4; ++n) bv[n] = *(const h16x8*)&lds[cb + bbase + n * 512];
#pragma unroll
    for (int m = 0; m < 4; ++m) av[m] = *(const h16x8*)&lds[cb + abase + m * 512];
    STAGE(T + 1, 0, 1);
    __builtin_amdgcn_s_barrier();
    asm volatile("s_waitcnt lgkmcnt(0)" ::: "memory");
    __builtin_amdgcn_s_setprio(1);
#pragma unroll
    for (int m = 0; m < 4; ++m)
#pragma unroll
      for (int n = 0; n < 4; ++n)
        acc[m][n] = __builtin_amdgcn_mfma_f32_16x16x32_f16(av[m], bv[n], acc[m][n], 0, 0, 0);
    __builtin_amdgcn_s_setprio(0);
    __builtin_amdgcn_s_barrier();
    // ---- q1: A m4-7 kh0 (B kh0 reused) ----
#pragma unroll
    for (int m = 0; m < 4; ++m) av[m] = *(const h16x8*)&lds[cb + abase + 2048 + m * 512];
    STAGE(T + 2, 1, 0);
    __builtin_amdgcn_s_barrier();
    asm volatile("s_waitcnt lgkmcnt(0)" ::: "memory");
    __builtin_amdgcn_s_setprio(1);
#pragma unroll
    for (int m = 0; m < 4; ++m)
#pragma unroll
      for (int n = 0; n < 4; ++n)
        acc[m + 4][n] = __builtin_amdgcn_mfma_f32_16x16x32_f16(av[m], bv[n], acc[m + 4][n], 0, 0, 0);
    __builtin_amdgcn_s_setprio(0);
    __builtin_amdgcn_s_barrier();
    // ---- q2: A m0-3 kh1 + B n0-3 kh1 ----
#pragma unroll
    for (int n = 0; n < 4; ++n) bv[n] = *(const h16x8*)&lds[cb + bbase + 8192 + n * 512];
#pragma unroll
    for (int m = 0; m < 4; ++m) av[m] = *(const h16x8*)&lds[cb + abase + 8192 + m * 512];
    STAGE(T + 2, 0, 0);
    __builtin_amdgcn_s_barrier();
    asm volatile("s_waitcnt lgkmcnt(0)" ::: "memory");
    __builtin_amdgcn_s_setprio(1);
#pragma unroll
    for (int m = 0; m < 4; ++m)
#pragma unroll
      for (int n = 0; n < 4; ++n)
        acc[m][n] = __builtin_amdgcn_mfma_f32_16x16x32_f16(av[m], bv[n], acc[m][n], 0, 0, 0);
    __builtin_amdgcn_s_setprio(0);
    __builtin_amdgcn_s_barrier();
    // ---- q3: A m4-7 kh1 ----
#pragma unroll
    for (int m = 0; m < 4; ++m) av[m] = *(const h16x8*)&lds[cb + abase + 8192 + 2048 + m * 512];
    STAGE(T + 2, 1, 1);
    if (drain)
      asm volatile("s_waitcnt vmcnt(0)" ::: "memory");
    else
      asm volatile("s_waitcnt vmcnt(6)" ::: "memory");  // tile T+1 resident
    __builtin_amdgcn_s_barrier();
    asm volatile("s_waitcnt lgkmcnt(0)" ::: "memory");
    __builtin_amdgcn_s_setprio(1);
#pragma unroll
    for (int m = 0; m < 4; ++m)
#pragma unroll
      for (int n = 0; n < 4; ++n)
        acc[m + 4][n] = __builtin_amdgcn_mfma_f32_16x16x32_f16(av[m], bv[n], acc[m + 4][n], 0, 0, 0);
    __builtin_amdgcn_s_setprio(0);
    __builtin_amdgcn_s_barrier();
  };

#pragma unroll 1
  for (int T = 0; T < NT; T += 2) {
    TILE(T, 0, T == NT - 2);
    TILE(T + 1, 1, T + 1 == NT - 1);
  }

  const size_t zc = (size_t)bz * cZ;
#pragma unroll
  for (int m = 0; m < 8; ++m)
#pragma unroll
    for (int n = 0; n < 4; ++n)
#pragma unroll
      for (int r = 0; r < 4; ++r) {
        int row = bm * 256 + wr * 128 + m * 16 + (lane >> 4) * 4 + r;
        int col = bn * 256 + wc * 64 + n * 16 + fr;
        float f = acc[m][n][r];
        if constexpr (EPI == 0) {
          ((h16*)Cp)[zc + (size_t)row * ldc + col] = (h16)f;
        } else if constexpr (EPI == 1) {
          ((float*)Cp)[zc + (size_t)row * ldc + col] = f * scale;
        } else {
          ((h16*)Cp)[zc + (size_t)row * ldc + col] = (h16)(f * scale);
        }
      }
}

// ---------------- row softmax + dropout mask -> P fp16 (all 8 batches) ----------
__global__ __launch_bounds__(256) void k_softmax(const h16* __restrict__ sc,
                                                 h16* __restrict__ P,
                                                 const int* __restrict__ mask) {
  const size_t rowp = blockIdx.x;  // 0..16383 (8 batches x 2048 rows)
  const h16* srow = sc + rowp * 2048;
  h16* prow = P + rowp * 2048;
  const int* mrow = mask + rowp * 2048;
  const int tid = threadIdx.x;
  h16x8 hv = ((const h16x8*)srow)[tid];
  float v[8];
#pragma unroll
  for (int j = 0; j < 8; ++j) v[j] = (float)hv[j];
  float m = v[0];
#pragma unroll
  for (int j = 1; j < 8; ++j) m = fmaxf(m, v[j]);
#pragma unroll
  for (int o = 32; o >= 1; o >>= 1) m = fmaxf(m, __shfl_xor(m, o));
  __shared__ float redm[4], reds[4];
  if ((tid & 63) == 0) redm[tid >> 6] = m;
  __syncthreads();
  m = fmaxf(fmaxf(redm[0], redm[1]), fmaxf(redm[2], redm[3]));
  float e[8], s = 0.f;
#pragma unroll
  for (int j = 0; j < 8; ++j) { e[j] = __expf(v[j] - m); s += e[j]; }
#pragma unroll
  for (int o = 32; o >= 1; o >>= 1) s += __shfl_xor(s, o);
  if ((tid & 63) == 0) reds[tid >> 6] = s;
  __syncthreads();
  s = reds[0] + reds[1] + reds[2] + reds[3];
  const float inv = 1.0f / (0.8f * s);
  i32x4 m0 = ((const i32x4*)mrow)[tid * 2];
  i32x4 m1 = ((const i32x4*)mrow)[tid * 2 + 1];
  int mm[8] = {m0[0], m0[1], m0[2], m0[3], m1[0], m1[1], m1[2], m1[3]};
  h16x8 o;
#pragma unroll
  for (int j = 0; j < 8; ++j) o[j] = mm[j] ? (h16)(e[j] * inv) : (h16)0.f;
  ((h16x8*)prow)[tid] = o;
}

extern "C" void kernel_launch(void* const* d_in, const int* in_sizes, int n_in,
                              void* d_out, int out_size, void* d_ws, size_t ws_size,
                              hipStream_t stream) {
  const float* x  = (const float*)d_in[0];
  const float* Wq = (const float*)d_in[1];
  const float* Wk = (const float*)d_in[2];
  const float* Wv = (const float*)d_in[3];
  const int* mask = (const int*)d_in[4];
  float* out = (float*)d_out;

  // ws layout (u16 elements), total 119,537,728 u16 = 239 MB (no aliasing):
  // [0]          xf   16384x1024 fp16
  // [16777216]   Wqk  1024x1024 fp16 (Wq rows 0-511 | Wk rows 512-1023)
  // [17825792]   Wvf  1024x1024 fp16
  // [18874368]   qk   16384x1024 fp16 (q cols 0-511 | k cols 512-1023)
  // [35651584]   vvt  1024x16384 fp16 (v^T, all batches)
  // [52428864]   P    8x2048x2048 fp16
  // [85983296]   sc   8x2048x2048 fp16 (scores)
  u16* ws = (u16*)d_ws;
  h16* xf  = (h16*)ws;
  h16* Wqk = (h16*)(ws + 16777216);
  h16* Wvf = (h16*)(ws + 17825792);
  h16* qk  = (h16*)(ws + 18874368);
  h16* vvt = (h16*)(ws + 35651584);
  h16* Pb  = (h16*)(ws + 52428864);
  h16* sch = (h16*)(ws + 85983296);

  k_cast_all<<<18432, 256, 0, stream>>>(x, Wq, Wk, Wv, xf, Wqk, Wvf);

  // q|k = x @ [Wq|Wk]^T  (K=1024) -> unified qk[t][1024]
  dim3 gqk(4, 64, 1);
  k_gemm<16, 0><<<gqk, 512, 0, stream>>>((const u16*)xf, 1024, 0,
                                         (const u16*)Wqk, 1024, 0, qk, 1024, 0, 0.f);

  // v^T = Wv @ x^T: C[g][t], coalesced
  dim3 gvt(64, 4, 1);
  k_gemm<16, 0><<<gvt, 512, 0, stream>>>((const u16*)Wvf, 1024, 0,
                                         (const u16*)xf, 1024, 0, vvt, 16384, 0, 0.f);

  // scores for all 8 batches in one launch (K=512): A=q, B=k (same buffer, +512)
  const float scale = 0.044194173824159216f;  // 1/sqrt(512)
  dim3 gs(8, 8, 8);
  k_gemm<8, 4><<<gs, 512, 0, stream>>>((const u16*)qk, 1024, 2097152,
                                       (const u16*)(qk + 512), 1024, 2097152,
                                       sch, 2048, 4194304, scale);

  // softmax + dropout mask -> P fp16, all 8 batches
  k_softmax<<<16384, 256, 0, stream>>>(sch, Pb, mask);

  // out = P @ (v^T)^T for all 8 batches in one launch (K=2048)
  dim3 gpv(4, 8, 8);
  k_gemm<32, 1><<<gpv, 512, 0, stream>>>((const u16*)Pb, 2048, 4194304,
                                         (const u16*)vvt, 16384, 2048,
                                         out, 1024, 2097152, 1.0f);

  (void)in_sizes; (void)n_in; (void)out_size; (void)ws_size;
}